// Round 11
// baseline (214.495 us; speedup 1.0000x reference)
//
#include <hip/hip_runtime.h>
#include <hip/hip_bf16.h>

#define DD 128

typedef __bf16 bf16x8v __attribute__((ext_vector_type(8)));
typedef float  f32x4   __attribute__((ext_vector_type(4)));

__device__ inline unsigned short f2bf(float f) {
    unsigned u = __builtin_bit_cast(unsigned, f);
    unsigned r = (u + 0x7fffu + ((u >> 16) & 1u)) >> 16;
    return (unsigned short)r;
}
__device__ inline float bflo2f(unsigned p) { return __builtin_bit_cast(float, p << 16); }
__device__ inline float bfhi2f(unsigned p) { return __builtin_bit_cast(float, p & 0xffff0000u); }
__device__ inline float rl_f(int v, int i) {
    return __builtin_bit_cast(float, __builtin_amdgcn_readlane(v, i));
}

// ---- zero cnt + fillc ----
__global__ __launch_bounds__(256) void k_zero(int* __restrict__ a, int* __restrict__ b, int N) {
    int i = blockIdx.x * 256 + threadIdx.x;
    int stride = gridDim.x * 256;
    for (; i < N; i += stride) { a[i] = 0; b[i] = 0; }
}

// ---- hist + fuse1 (Wf = Wv@Wo, bfo = bv@Wo + bo) in one dispatch ----
__global__ __launch_bounds__(256) void k_hist_fuse1(const int* __restrict__ dst, int* __restrict__ cnt,
                                                    int E, int N,
                                                    const float* __restrict__ Wv, const float* __restrict__ Wo,
                                                    const float* __restrict__ bv, const float* __restrict__ bo,
                                                    float* __restrict__ Wf, float* __restrict__ bfo, int EB) {
    if ((int)blockIdx.x < EB) {
        int e = blockIdx.x * 256 + threadIdx.x;
        if (e < E) {
            int d = dst[e];
            if ((unsigned)d < (unsigned)N) atomicAdd(&cnt[d], 1);
        }
    } else {
        int gid = (blockIdx.x - EB) * 256 + threadIdx.x;
        if (gid >= (DD + 1) * DD) return;
        int i = gid >> 7, j = gid & (DD - 1);
        if (i < DD) {
            float acc = 0.f;
            for (int k = 0; k < DD; ++k) acc = fmaf(Wv[i * DD + k], Wo[k * DD + j], acc);
            Wf[i * DD + j] = acc;
        } else {
            float acc = bo[j];
            for (int k = 0; k < DD; ++k) acc = fmaf(bv[k], Wo[k * DD + j], acc);
            bfo[j] = acc;
        }
    }
}

// ---- block scan + weight prep (W2f^T bf16, bf2, Wt1) in one dispatch ----
__global__ __launch_bounds__(256) void k_scanblk_wprep(const int* __restrict__ cnt, int* __restrict__ rowptr,
                                                       int* __restrict__ bsums, int N, int nb,
                                                       const float* __restrict__ W2, const float* __restrict__ Wf,
                                                       const float* __restrict__ b2, const float* __restrict__ bfo,
                                                       unsigned short* __restrict__ W2ft, float* __restrict__ bf2,
                                                       const float* __restrict__ W1, unsigned short* __restrict__ Wt1) {
    if ((int)blockIdx.x < nb) {
        __shared__ int sh[256];
        int t = threadIdx.x;
        int gid = blockIdx.x * 256 + t;
        int v = (gid < N) ? cnt[gid] : 0;
        sh[t] = v;
        __syncthreads();
        #pragma unroll
        for (int off = 1; off < 256; off <<= 1) {
            int add = (t >= off) ? sh[t - off] : 0;
            __syncthreads();
            sh[t] += add;
            __syncthreads();
        }
        if (gid < N) rowptr[gid] = sh[t] - v;
        if (t == 255) bsums[blockIdx.x] = sh[255];
    } else {
        int blk = blockIdx.x - nb;
        if (blk < 65) {
            int gid = blk * 256 + threadIdx.x;
            if (gid >= (DD + 1) * DD) return;
            int i = gid >> 7, j = gid & (DD - 1);
            if (i < DD) {
                float acc = 0.f;
                for (int k = 0; k < DD; ++k) acc = fmaf(W2[i * DD + k], Wf[k * DD + j], acc);
                W2ft[j * DD + i] = f2bf(acc);       // transposed bf16
            } else {
                float acc = bfo[j];
                for (int k = 0; k < DD; ++k) acc = fmaf(b2[k], Wf[k * DD + j], acc);
                bf2[j] = acc;
            }
        } else {
            int gid = (blk - 65) * 256 + threadIdx.x;   // 16384
            int k = gid >> 7, n = gid & 127;
            Wt1[n * DD + k] = f2bf(W1[k * DD + n]);
        }
    }
}

// ---- scan finalize with inline bsums scan ----
__global__ __launch_bounds__(256) void k_scan_add2(int* __restrict__ rowptr, const int* __restrict__ bsums,
                                                   const int* __restrict__ cnt, float* __restrict__ dinv,
                                                   int N, int nb) {
    __shared__ int sh[512];
    int t = threadIdx.x;
    sh[t]       = (t < nb)       ? bsums[t]       : 0;
    sh[t + 256] = (t + 256 < nb) ? bsums[t + 256] : 0;
    __syncthreads();
    #pragma unroll
    for (int off = 1; off < 512; off <<= 1) {
        int a = (t >= off)       ? sh[t - off]       : 0;
        int b = (t + 256 >= off) ? sh[t + 256 - off] : 0;
        __syncthreads();
        sh[t] += a;
        sh[t + 256] += b;
        __syncthreads();
    }
    int b = blockIdx.x;
    int pfx = (b == 0) ? 0 : sh[b - 1];
    int gid = b * 256 + t;
    if (gid < N) {
        int c = cnt[gid];
        int v = rowptr[gid] + pfx;
        rowptr[gid] = v;
        if (gid == N - 1) rowptr[N] = v + c;
        dinv[gid] = rsqrtf(1.0f + (float)c);
    }
}

// ---- fill CSR: ev[pos] = (src, bits(norm)) grouped by dst ----
__global__ __launch_bounds__(256) void k_fill(const int* __restrict__ src, const int* __restrict__ dst,
                                              const int* __restrict__ rowptr, int* __restrict__ fillc,
                                              const float* __restrict__ dinv,
                                              int2* __restrict__ ev, int E, int N) {
    int e = blockIdx.x * 256 + threadIdx.x;
    if (e >= E) return;
    int s = src[e], d = dst[e];
    if ((unsigned)s >= (unsigned)N || (unsigned)d >= (unsigned)N) return;
    int pos = rowptr[d] + atomicAdd(&fillc[d], 1);
    float nm = dinv[s] * dinv[d];
    ev[pos] = make_int2(s, __builtin_bit_cast(int, nm));
}

// ---- MFMA GEMM: Cb[M x 128] bf16 = A[M x 128] @ Wt^T ----
// B fragments preloaded in registers; no LDS, no syncthreads.
// Layouts (m89/m91): a/b frag: idx=l&15, k=(l>>4)*8+j; D: col=l&15, row=(l>>4)*4+reg.
template<int AF32>
__global__ __launch_bounds__(256, 2) void k_gemm_mfma(const void* __restrict__ Av,
                                                      const unsigned short* __restrict__ Wt,
                                                      unsigned short* __restrict__ Cb, int M) {
    int w  = threadIdx.x >> 6;
    int l  = threadIdx.x & 63;
    int lr = l & 15, lg = l >> 4;

    bf16x8v bfr[8][4];
    #pragma unroll
    for (int nt = 0; nt < 8; ++nt)
        #pragma unroll
        for (int kk = 0; kk < 4; ++kk)
            bfr[nt][kk] = *reinterpret_cast<const bf16x8v*>(Wt + (nt * 16 + lr) * DD + kk * 32 + lg * 8);

    int tiles = (M + 63) >> 6;
    for (int t = blockIdx.x; t < tiles; t += gridDim.x) {
        int m0 = t * 64 + w * 16;
        int row = m0 + lr;
        int rowc = row < M ? row : (M - 1);

        bf16x8v af[4];
        if (AF32) {
            const float* Af = (const float*)Av;
            #pragma unroll
            for (int kk = 0; kk < 4; ++kk) {
                const float* p = Af + (size_t)rowc * DD + kk * 32 + lg * 8;
                float4 u0 = *reinterpret_cast<const float4*>(p);
                float4 u1 = *reinterpret_cast<const float4*>(p + 4);
                af[kk][0] = (__bf16)u0.x; af[kk][1] = (__bf16)u0.y;
                af[kk][2] = (__bf16)u0.z; af[kk][3] = (__bf16)u0.w;
                af[kk][4] = (__bf16)u1.x; af[kk][5] = (__bf16)u1.y;
                af[kk][6] = (__bf16)u1.z; af[kk][7] = (__bf16)u1.w;
            }
        } else {
            const unsigned short* Ab = (const unsigned short*)Av;
            #pragma unroll
            for (int kk = 0; kk < 4; ++kk)
                af[kk] = *reinterpret_cast<const bf16x8v*>(Ab + (size_t)rowc * DD + kk * 32 + lg * 8);
        }

        f32x4 acc[8] = {};
        #pragma unroll
        for (int kk = 0; kk < 4; ++kk)
            #pragma unroll
            for (int nt = 0; nt < 8; ++nt)
                acc[nt] = __builtin_amdgcn_mfma_f32_16x16x32_bf16(af[kk], bfr[nt][kk], acc[nt], 0, 0, 0);

        #pragma unroll
        for (int nt = 0; nt < 8; ++nt)
            #pragma unroll
            for (int r = 0; r < 4; ++r) {
                int rr = m0 + lg * 4 + r;
                if (rr < M) Cb[(size_t)rr * DD + nt * 16 + lr] = f2bf(acc[nt][r]);
            }
    }
}

// ---- CSR gather: half-split. Lanes 0-31 = row A, 32-63 = row B. ----
// Each lane loads uint2 (4 features); one load instr gathers for TWO rows.
// 8 rows/wave as 4 pairs, chunk prefetched one pair ahead.
template<int OUTF32, int RELU>
__global__ __launch_bounds__(256) void k_gather_hs(const int* __restrict__ rowptr, const int2* __restrict__ ev,
                                                   const uint2* __restrict__ h2, const float* __restrict__ dinv,
                                                   const float* __restrict__ bias, void* __restrict__ outp,
                                                   int N, int E) {
    int l = threadIdx.x & 63;
    int wv = blockIdx.x * 4 + (threadIdx.x >> 6);
    int m0 = wv * 8;
    if (m0 >= N) return;
    int hh = l >> 5;          // 0: row A, 1: row B
    int q  = l & 31;
    float4 bb = reinterpret_cast<const float4*>(bias)[q];

    // preload 9 rowptrs (lanes 0..8), 8 dinv (lanes 0..7)
    int rpidx = m0 + l; if (rpidx > N) rpidx = N;
    int rp = (l < 9) ? rowptr[rpidx] : 0;
    int dvidx = m0 + l; if (dvidx >= N) dvidx = N - 1;
    float dv = (l < 8) ? dinv[dvidx] : 0.f;

    // prefetch chunk for pair 0: lanes 0-31 row A edges, 32-63 row B edges
    int2 me;
    {
        int bA = __builtin_amdgcn_readlane(rp, 0);
        int eA = __builtin_amdgcn_readlane(rp, 1);
        int eB = __builtin_amdgcn_readlane(rp, 2);
        int cA = eA - bA; if (cA > 32) cA = 32;
        int cB = eB - eA; if (cB > 32) cB = 32;
        int iA = bA + (q < cA ? q : (cA > 0 ? cA - 1 : 0)); if (iA >= E) iA = E - 1;
        int iB = eA + (q < cB ? q : (cB > 0 ? cB - 1 : 0)); if (iB >= E) iB = E - 1;
        me = ev[hh ? iB : iA];
    }

    #pragma unroll
    for (int t = 0; t < 4; ++t) {
        int nA = m0 + 2 * t, nB = nA + 1;
        int bA = __builtin_amdgcn_readlane(rp, 2 * t);
        int eA = __builtin_amdgcn_readlane(rp, 2 * t + 1);
        int eB = __builtin_amdgcn_readlane(rp, 2 * t + 2);
        int degA = eA - bA, degB = eB - eA;
        int cA = degA < 32 ? degA : 32;
        int cB = degB < 32 ? degB : 32;
        int2 mc = me;
        if (t < 3) {   // prefetch next pair's chunk
            int bA2 = __builtin_amdgcn_readlane(rp, 2 * t + 2);
            int eA2 = __builtin_amdgcn_readlane(rp, 2 * t + 3);
            int eB2 = __builtin_amdgcn_readlane(rp, 2 * t + 4);
            int cA2 = eA2 - bA2; if (cA2 > 32) cA2 = 32;
            int cB2 = eB2 - eA2; if (cB2 > 32) cB2 = 32;
            int iA = bA2 + (q < cA2 ? q : (cA2 > 0 ? cA2 - 1 : 0)); if (iA >= E) iA = E - 1;
            int iB = eA2 + (q < cB2 ? q : (cB2 > 0 ? cB2 - 1 : 0)); if (iB >= E) iB = E - 1;
            me = ev[hh ? iB : iA];
        }

        float a0 = 0.f, a1 = 0.f, a2 = 0.f, a3 = 0.f;
        int cmax = cA > cB ? cA : cB;
        for (int i = 0; i < cmax; i += 8) {
            uint2 p[8]; float w[8];
            #pragma unroll
            for (int j = 0; j < 8; ++j) {
                int jA = i + j; if (jA >= cA) jA = cA - 1; if (jA < 0) jA = 0;
                int jB = i + j; if (jB >= cB) jB = cB - 1; if (jB < 0) jB = 0;
                int sA = __builtin_amdgcn_readlane(mc.x, jA);
                int sB = __builtin_amdgcn_readlane(mc.x, 32 + jB);
                float wA = rl_f(mc.y, jA);
                float wB = rl_f(mc.y, 32 + jB);
                int s  = hh ? sB : sA;
                int cc = hh ? cB : cA;
                p[j] = h2[(size_t)s * 32 + q];
                w[j] = (i + j < cc) ? (hh ? wB : wA) : 0.f;
            }
            #pragma unroll
            for (int j = 0; j < 8; ++j) {
                a0 = fmaf(w[j], bflo2f(p[j].x), a0);
                a1 = fmaf(w[j], bfhi2f(p[j].x), a1);
                a2 = fmaf(w[j], bflo2f(p[j].y), a2);
                a3 = fmaf(w[j], bfhi2f(p[j].y), a3);
            }
        }
        // rare tail: deg > 32
        int degmax = degA > degB ? degA : degB;
        for (int base = 32; base < degmax; base += 32) {
            int c2A = degA - base; if (c2A > 32) c2A = 32;
            int c2B = degB - base; if (c2B > 32) c2B = 32;
            int iA = bA + base + (q < c2A ? q : (c2A > 0 ? c2A - 1 : 0));
            if (iA >= E) iA = E - 1; if (iA < bA) iA = bA;
            int iB = eA + base + (q < c2B ? q : (c2B > 0 ? c2B - 1 : 0));
            if (iB >= E) iB = E - 1; if (iB < eA) iB = eA;
            int2 m2 = ev[hh ? iB : iA];
            int c2m = c2A > c2B ? c2A : c2B;
            for (int j = 0; j < c2m; ++j) {
                int jA = j; if (jA >= c2A) jA = c2A > 0 ? c2A - 1 : 0;
                int jB = j; if (jB >= c2B) jB = c2B > 0 ? c2B - 1 : 0;
                int sA = __builtin_amdgcn_readlane(m2.x, jA);
                int sB = __builtin_amdgcn_readlane(m2.x, 32 + jB);
                float wA = rl_f(m2.y, jA);
                float wB = rl_f(m2.y, 32 + jB);
                int s  = hh ? sB : sA;
                int cc = hh ? c2B : c2A;
                uint2 pp = h2[(size_t)s * 32 + q];
                float wq = (j < cc) ? (hh ? wB : wA) : 0.f;
                a0 = fmaf(wq, bflo2f(pp.x), a0);
                a1 = fmaf(wq, bfhi2f(pp.x), a1);
                a2 = fmaf(wq, bflo2f(pp.y), a2);
                a3 = fmaf(wq, bfhi2f(pp.y), a3);
            }
        }

        // self loop + bias + activation + write
        int nS = hh ? nB : nA;
        int nSc = nS < N ? nS : N - 1;
        uint2 ps = h2[(size_t)nSc * 32 + q];
        float diA = __builtin_bit_cast(float, __builtin_amdgcn_readlane(__builtin_bit_cast(int, dv), 2 * t));
        float diB = __builtin_bit_cast(float, __builtin_amdgcn_readlane(__builtin_bit_cast(int, dv), 2 * t + 1));
        float di = hh ? diB : diA;
        float di2 = di * di;
        a0 = fmaf(di2, bflo2f(ps.x), a0) + bb.x;
        a1 = fmaf(di2, bfhi2f(ps.x), a1) + bb.y;
        a2 = fmaf(di2, bflo2f(ps.y), a2) + bb.z;
        a3 = fmaf(di2, bfhi2f(ps.y), a3) + bb.w;
        if (RELU) {
            a0 = fmaxf(a0, 0.f); a1 = fmaxf(a1, 0.f);
            a2 = fmaxf(a2, 0.f); a3 = fmaxf(a3, 0.f);
        }
        if (nS < N) {
            if (OUTF32) {
                reinterpret_cast<float4*>(outp)[(size_t)nS * 32 + q] = make_float4(a0, a1, a2, a3);
            } else {
                uint2 po;
                po.x = (unsigned)f2bf(a0) | ((unsigned)f2bf(a1) << 16);
                po.y = (unsigned)f2bf(a2) | ((unsigned)f2bf(a3) << 16);
                reinterpret_cast<uint2*>(outp)[(size_t)nS * 32 + q] = po;
            }
        }
    }
}

extern "C" void kernel_launch(void* const* d_in, const int* in_sizes, int n_in,
                              void* d_out, int out_size, void* d_ws, size_t ws_size,
                              hipStream_t stream) {
    const float* x  = (const float*)d_in[0];
    const int*   ei = (const int*)d_in[1];
    const float* W1 = (const float*)d_in[2];
    const float* b1 = (const float*)d_in[3];
    const float* W2 = (const float*)d_in[4];
    const float* b2 = (const float*)d_in[5];
    // Wq/bq/Wk/bk (6..9) dead: softmax over seq_len=1 is identity.
    const float* Wv = (const float*)d_in[10];
    const float* bv = (const float*)d_in[11];
    const float* Wo = (const float*)d_in[12];
    const float* bo = (const float*)d_in[13];
    int N = in_sizes[0] / DD;
    int E = in_sizes[1] / 2;
    const int* src = ei;
    const int* dst = ei + E;
    float* out = (float*)d_out;

    unsigned* hA  = (unsigned*)d_ws;                  // N*64 u32 (bf16 GEMM out)
    unsigned* h1  = hA + (size_t)N * 64;              // N*64 u32 (bf16 h1)
    float* dinv   = (float*)(h1 + (size_t)N * 64);    // N
    float* Wf     = dinv + N;                         // 128*128 f32
    float* bfo    = Wf + DD * DD;                     // 128
    float* bf2    = bfo + DD;                         // 128
    unsigned short* Wt1  = (unsigned short*)(bf2 + DD);   // 128*128 bf16
    unsigned short* W2ft = Wt1 + DD * DD;                 // 128*128 bf16
    int* cnt    = (int*)(W2ft + DD * DD);             // N
    int* fillc  = cnt + N;                            // N
    int* rowptr = fillc + N;                          // N+1
    int* bsums  = rowptr + N + 1;                     // 512
    int2* ev    = (int2*)(((uintptr_t)(bsums + 512) + 15) & ~(uintptr_t)15);  // E

    int nb = (N + 255) / 256;
    int EB = (E + 255) / 256;

    // D1: zero counters
    k_zero<<<512, 256, 0, stream>>>(cnt, fillc, N);
    // D2: degree histogram + MHA weight fold (independent block ranges)
    k_hist_fuse1<<<EB + 129, 256, 0, stream>>>(dst, cnt, E, N, Wv, Wo, bv, bo, Wf, bfo, EB);
    // D3: block-level scan + weight transposes (needs Wf from D2)
    k_scanblk_wprep<<<nb + 129, 256, 0, stream>>>(cnt, rowptr, bsums, N, nb,
                                                  W2, Wf, b2, bfo, W2ft, bf2, W1, Wt1);
    // D4: scan finalize (inline bsums scan) + dinv
    k_scan_add2<<<nb, 256, 0, stream>>>(rowptr, bsums, cnt, dinv, N, nb);
    // D5: CSR fill (standalone — hetero-fusion with GEMM regressed in R10)
    k_fill<<<EB, 256, 0, stream>>>(src, dst, rowptr, fillc, dinv, ev, E, N);
    // D6: layer-1 GEMM: hA = bf16(x @ W1)
    k_gemm_mfma<1><<<1280, 256, 0, stream>>>(x, Wt1, (unsigned short*)hA, N);
    int gb = ((N + 7) / 8 + 3) / 4;   // 4 waves/block, 8 rows/wave
    // D7: gather layer 1 -> h1 (bf16, relu, +b1)
    k_gather_hs<0, 1><<<gb, 256, 0, stream>>>(rowptr, ev, (const uint2*)hA, dinv, b1, h1, N, E);
    // D8: layer-2 GEMM (W2·Wv·Wo folded): hA = bf16(h1 @ W2f)
    k_gemm_mfma<0><<<1280, 256, 0, stream>>>(h1, W2ft, (unsigned short*)hA, N);
    // D9: gather layer 2 -> out (f32, +bf2)
    k_gather_hs<1, 0><<<gb, 256, 0, stream>>>(rowptr, ev, (const uint2*)hA, dinv, bf2, out, N, E);
}

// Round 12
// 188.865 us; speedup vs baseline: 1.1357x; 1.1357x over previous
//
#include <hip/hip_runtime.h>
#include <hip/hip_bf16.h>

#define DD 128

typedef __bf16 bf16x8v __attribute__((ext_vector_type(8)));
typedef float  f32x4   __attribute__((ext_vector_type(4)));

__device__ inline unsigned short f2bf(float f) {
    unsigned u = __builtin_bit_cast(unsigned, f);
    unsigned r = (u + 0x7fffu + ((u >> 16) & 1u)) >> 16;
    return (unsigned short)r;
}
__device__ inline float bflo2f(unsigned p) { return __builtin_bit_cast(float, p << 16); }
__device__ inline float bfhi2f(unsigned p) { return __builtin_bit_cast(float, p & 0xffff0000u); }
__device__ inline float rl_f(int v, int i) {
    return __builtin_bit_cast(float, __builtin_amdgcn_readlane(v, i));
}

// ---- zero cnt + fillc ----
__global__ __launch_bounds__(256) void k_zero(int* __restrict__ a, int* __restrict__ b, int N) {
    int i = blockIdx.x * 256 + threadIdx.x;
    int stride = gridDim.x * 256;
    for (; i < N; i += stride) { a[i] = 0; b[i] = 0; }
}

// ---- hist + fuse1 (Wf = Wv@Wo, bfo = bv@Wo + bo) in one dispatch ----
__global__ __launch_bounds__(256) void k_hist_fuse1(const int* __restrict__ dst, int* __restrict__ cnt,
                                                    int E, int N,
                                                    const float* __restrict__ Wv, const float* __restrict__ Wo,
                                                    const float* __restrict__ bv, const float* __restrict__ bo,
                                                    float* __restrict__ Wf, float* __restrict__ bfo, int EB) {
    if ((int)blockIdx.x < EB) {
        int e = blockIdx.x * 256 + threadIdx.x;
        if (e < E) {
            int d = dst[e];
            if ((unsigned)d < (unsigned)N) atomicAdd(&cnt[d], 1);
        }
    } else {
        int gid = (blockIdx.x - EB) * 256 + threadIdx.x;
        if (gid >= (DD + 1) * DD) return;
        int i = gid >> 7, j = gid & (DD - 1);
        if (i < DD) {
            float acc = 0.f;
            for (int k = 0; k < DD; ++k) acc = fmaf(Wv[i * DD + k], Wo[k * DD + j], acc);
            Wf[i * DD + j] = acc;
        } else {
            float acc = bo[j];
            for (int k = 0; k < DD; ++k) acc = fmaf(bv[k], Wo[k * DD + j], acc);
            bfo[j] = acc;
        }
    }
}

// ---- block scan + weight prep (W2f^T bf16, bf2, Wt1) in one dispatch ----
__global__ __launch_bounds__(256) void k_scanblk_wprep(const int* __restrict__ cnt, int* __restrict__ rowptr,
                                                       int* __restrict__ bsums, int N, int nb,
                                                       const float* __restrict__ W2, const float* __restrict__ Wf,
                                                       const float* __restrict__ b2, const float* __restrict__ bfo,
                                                       unsigned short* __restrict__ W2ft, float* __restrict__ bf2,
                                                       const float* __restrict__ W1, unsigned short* __restrict__ Wt1) {
    if ((int)blockIdx.x < nb) {
        __shared__ int sh[256];
        int t = threadIdx.x;
        int gid = blockIdx.x * 256 + t;
        int v = (gid < N) ? cnt[gid] : 0;
        sh[t] = v;
        __syncthreads();
        #pragma unroll
        for (int off = 1; off < 256; off <<= 1) {
            int add = (t >= off) ? sh[t - off] : 0;
            __syncthreads();
            sh[t] += add;
            __syncthreads();
        }
        if (gid < N) rowptr[gid] = sh[t] - v;
        if (t == 255) bsums[blockIdx.x] = sh[255];
    } else {
        int blk = blockIdx.x - nb;
        if (blk < 65) {
            int gid = blk * 256 + threadIdx.x;
            if (gid >= (DD + 1) * DD) return;
            int i = gid >> 7, j = gid & (DD - 1);
            if (i < DD) {
                float acc = 0.f;
                for (int k = 0; k < DD; ++k) acc = fmaf(W2[i * DD + k], Wf[k * DD + j], acc);
                W2ft[j * DD + i] = f2bf(acc);       // transposed bf16
            } else {
                float acc = bfo[j];
                for (int k = 0; k < DD; ++k) acc = fmaf(b2[k], Wf[k * DD + j], acc);
                bf2[j] = acc;
            }
        } else {
            int gid = (blk - 65) * 256 + threadIdx.x;   // 16384
            int k = gid >> 7, n = gid & 127;
            Wt1[n * DD + k] = f2bf(W1[k * DD + n]);
        }
    }
}

// ---- scan finalize with inline bsums scan ----
__global__ __launch_bounds__(256) void k_scan_add2(int* __restrict__ rowptr, const int* __restrict__ bsums,
                                                   const int* __restrict__ cnt, float* __restrict__ dinv,
                                                   int N, int nb) {
    __shared__ int sh[512];
    int t = threadIdx.x;
    sh[t]       = (t < nb)       ? bsums[t]       : 0;
    sh[t + 256] = (t + 256 < nb) ? bsums[t + 256] : 0;
    __syncthreads();
    #pragma unroll
    for (int off = 1; off < 512; off <<= 1) {
        int a = (t >= off)       ? sh[t - off]       : 0;
        int b = (t + 256 >= off) ? sh[t + 256 - off] : 0;
        __syncthreads();
        sh[t] += a;
        sh[t + 256] += b;
        __syncthreads();
    }
    int b = blockIdx.x;
    int pfx = (b == 0) ? 0 : sh[b - 1];
    int gid = b * 256 + t;
    if (gid < N) {
        int c = cnt[gid];
        int v = rowptr[gid] + pfx;
        rowptr[gid] = v;
        if (gid == N - 1) rowptr[N] = v + c;
        dinv[gid] = rsqrtf(1.0f + (float)c);
    }
}

// ---- fill CSR: ev[pos] = (src, bits(norm)) grouped by dst ----
__global__ __launch_bounds__(256) void k_fill(const int* __restrict__ src, const int* __restrict__ dst,
                                              const int* __restrict__ rowptr, int* __restrict__ fillc,
                                              const float* __restrict__ dinv,
                                              int2* __restrict__ ev, int E, int N) {
    int e = blockIdx.x * 256 + threadIdx.x;
    if (e >= E) return;
    int s = src[e], d = dst[e];
    if ((unsigned)s >= (unsigned)N || (unsigned)d >= (unsigned)N) return;
    int pos = rowptr[d] + atomicAdd(&fillc[d], 1);
    float nm = dinv[s] * dinv[d];
    ev[pos] = make_int2(s, __builtin_bit_cast(int, nm));
}

// ---- MFMA GEMM: Cb[M x 128] bf16 = A[M x 128] @ Wt^T ----
// B fragments preloaded in registers; no LDS, no syncthreads. Grid 512 (proven R9).
// Layouts (m89/m91): a/b frag: idx=l&15, k=(l>>4)*8+j; D: col=l&15, row=(l>>4)*4+reg.
template<int AF32>
__global__ __launch_bounds__(256, 2) void k_gemm_mfma(const void* __restrict__ Av,
                                                      const unsigned short* __restrict__ Wt,
                                                      unsigned short* __restrict__ Cb, int M) {
    int w  = threadIdx.x >> 6;
    int l  = threadIdx.x & 63;
    int lr = l & 15, lg = l >> 4;

    bf16x8v bfr[8][4];
    #pragma unroll
    for (int nt = 0; nt < 8; ++nt)
        #pragma unroll
        for (int kk = 0; kk < 4; ++kk)
            bfr[nt][kk] = *reinterpret_cast<const bf16x8v*>(Wt + (nt * 16 + lr) * DD + kk * 32 + lg * 8);

    int tiles = (M + 63) >> 6;
    for (int t = blockIdx.x; t < tiles; t += gridDim.x) {
        int m0 = t * 64 + w * 16;
        int row = m0 + lr;
        int rowc = row < M ? row : (M - 1);

        bf16x8v af[4];
        if (AF32) {
            const float* Af = (const float*)Av;
            #pragma unroll
            for (int kk = 0; kk < 4; ++kk) {
                const float* p = Af + (size_t)rowc * DD + kk * 32 + lg * 8;
                float4 u0 = *reinterpret_cast<const float4*>(p);
                float4 u1 = *reinterpret_cast<const float4*>(p + 4);
                af[kk][0] = (__bf16)u0.x; af[kk][1] = (__bf16)u0.y;
                af[kk][2] = (__bf16)u0.z; af[kk][3] = (__bf16)u0.w;
                af[kk][4] = (__bf16)u1.x; af[kk][5] = (__bf16)u1.y;
                af[kk][6] = (__bf16)u1.z; af[kk][7] = (__bf16)u1.w;
            }
        } else {
            const unsigned short* Ab = (const unsigned short*)Av;
            #pragma unroll
            for (int kk = 0; kk < 4; ++kk)
                af[kk] = *reinterpret_cast<const bf16x8v*>(Ab + (size_t)rowc * DD + kk * 32 + lg * 8);
        }

        f32x4 acc[8] = {};
        #pragma unroll
        for (int kk = 0; kk < 4; ++kk)
            #pragma unroll
            for (int nt = 0; nt < 8; ++nt)
                acc[nt] = __builtin_amdgcn_mfma_f32_16x16x32_bf16(af[kk], bfr[nt][kk], acc[nt], 0, 0, 0);

        #pragma unroll
        for (int nt = 0; nt < 8; ++nt)
            #pragma unroll
            for (int r = 0; r < 4; ++r) {
                int rr = m0 + lg * 4 + r;
                if (rr < M) Cb[(size_t)rr * DD + nt * 16 + lr] = f2bf(acc[nt][r]);
            }
    }
}

// ---- CSR gather (R9-proven): 8 rows/wave, 2-row software pipeline ----
template<int OUTF32, int RELU>
__global__ __launch_bounds__(256) void k_gather8(const int* __restrict__ rowptr, const int2* __restrict__ ev,
                                                 const unsigned* __restrict__ h32, const float* __restrict__ dinv,
                                                 const float* __restrict__ bias, void* __restrict__ outp, int N) {
    int l = threadIdx.x & 63;
    int g = blockIdx.x * 4 + (threadIdx.x >> 6);   // 8-row group id
    int m0 = g * 8;
    if (m0 >= N) return;
    float2 bb = reinterpret_cast<const float2*>(bias)[l];

    // preload 9 row ptrs (lanes 0..8) and 8 dinv (lanes 0..7)
    int rpidx = m0 + l; if (rpidx > N) rpidx = N;
    int rp = (l < 9) ? rowptr[rpidx] : 0;
    int dvidx = m0 + l; if (dvidx >= N) dvidx = N - 1;
    float dv = (l < 8) ? dinv[dvidx] : 0.f;

    // prefetch edge chunks for rows 0,1
    int2 me0, me1;
    {
        int b0 = __builtin_amdgcn_readlane(rp, 0), e0 = __builtin_amdgcn_readlane(rp, 1);
        int c0 = e0 - b0; if (c0 > 64) c0 = 64;
        me0 = (c0 > 0) ? ev[b0 + (l < c0 ? l : c0 - 1)] : make_int2(0, 0);
        int b1 = e0, e1 = __builtin_amdgcn_readlane(rp, 2);
        int c1 = e1 - b1; if (c1 > 64) c1 = 64;
        me1 = (c1 > 0) ? ev[b1 + (l < c1 ? l : c1 - 1)] : make_int2(0, 0);
    }

    #pragma unroll
    for (int r = 0; r < 8; r += 2) {
        int nA = m0 + r, nB = m0 + r + 1;
        int bA = __builtin_amdgcn_readlane(rp, r);
        int eA = __builtin_amdgcn_readlane(rp, r + 1);
        int eB = __builtin_amdgcn_readlane(rp, r + 2);
        int degA = eA - bA, degB = eB - eA;
        int bB = eA;
        int2 mA = me0, mB = me1;
        if (r + 2 < 8) {   // prefetch next pair's chunks (independent loads)
            int b2 = __builtin_amdgcn_readlane(rp, r + 2), e2 = __builtin_amdgcn_readlane(rp, r + 3);
            int c2 = e2 - b2; if (c2 > 64) c2 = 64;
            me0 = (c2 > 0) ? ev[b2 + (l < c2 ? l : c2 - 1)] : make_int2(0, 0);
            int b3 = e2, e3 = __builtin_amdgcn_readlane(rp, r + 4);
            int c3 = e3 - b3; if (c3 > 64) c3 = 64;
            me1 = (c3 > 0) ? ev[b3 + (l < c3 ? l : c3 - 1)] : make_int2(0, 0);
        }

        int cA = degA < 64 ? degA : 64;
        int cB = degB < 64 ? degB : 64;
        int fA = cA < 8 ? cA : 8;
        int fB = cB < 8 ? cB : 8;

        // issue ALL first-round loads for both rows + self rows before any use
        unsigned pA[8], pB[8]; float wA[8], wB[8];
        #pragma unroll
        for (int q = 0; q < 8; ++q) {
            int ia = (q < fA) ? q : (fA > 0 ? fA - 1 : 0);
            int s = __builtin_amdgcn_readlane(mA.x, ia);
            pA[q] = h32[(size_t)s * 64 + l];
            wA[q] = (q < fA) ? rl_f(mA.y, ia) : 0.f;
        }
        #pragma unroll
        for (int q = 0; q < 8; ++q) {
            int ib = (q < fB) ? q : (fB > 0 ? fB - 1 : 0);
            int s = __builtin_amdgcn_readlane(mB.x, ib);
            pB[q] = h32[(size_t)s * 64 + l];
            wB[q] = (q < fB) ? rl_f(mB.y, ib) : 0.f;
        }
        unsigned psA = h32[(size_t)(nA < N ? nA : N - 1) * 64 + l];
        unsigned psB = h32[(size_t)(nB < N ? nB : N - 1) * 64 + l];

        float axA = 0.f, ayA = 0.f, axB = 0.f, ayB = 0.f;
        #pragma unroll
        for (int q = 0; q < 8; ++q) {
            axA = fmaf(wA[q], bflo2f(pA[q]), axA);
            ayA = fmaf(wA[q], bfhi2f(pA[q]), ayA);
            axB = fmaf(wB[q], bflo2f(pB[q]), axB);
            ayB = fmaf(wB[q], bfhi2f(pB[q]), ayB);
        }

        // deg in (8,64]: continue within prefetched chunks
        for (int i = 8; i < cA; i += 8) {
            #pragma unroll
            for (int q = 0; q < 8; ++q) {
                int ia = (i + q < cA) ? i + q : cA - 1;
                int s = __builtin_amdgcn_readlane(mA.x, ia);
                unsigned p = h32[(size_t)s * 64 + l];
                float wq = (i + q < cA) ? rl_f(mA.y, ia) : 0.f;
                axA = fmaf(wq, bflo2f(p), axA);
                ayA = fmaf(wq, bfhi2f(p), ayA);
            }
        }
        for (int i = 8; i < cB; i += 8) {
            #pragma unroll
            for (int q = 0; q < 8; ++q) {
                int ib = (i + q < cB) ? i + q : cB - 1;
                int s = __builtin_amdgcn_readlane(mB.x, ib);
                unsigned p = h32[(size_t)s * 64 + l];
                float wq = (i + q < cB) ? rl_f(mB.y, ib) : 0.f;
                axB = fmaf(wq, bflo2f(p), axB);
                ayB = fmaf(wq, bfhi2f(p), ayB);
            }
        }
        // deg > 64: rare serial tail
        for (int base = 64; base < degA; base += 64) {
            int cc = degA - base; if (cc > 64) cc = 64;
            int2 m2 = ev[bA + base + (l < cc ? l : cc - 1)];
            for (int ii = 0; ii < cc; ++ii) {
                int s = __builtin_amdgcn_readlane(m2.x, ii);
                unsigned p = h32[(size_t)s * 64 + l];
                float wq = rl_f(m2.y, ii);
                axA = fmaf(wq, bflo2f(p), axA);
                ayA = fmaf(wq, bfhi2f(p), ayA);
            }
        }
        for (int base = 64; base < degB; base += 64) {
            int cc = degB - base; if (cc > 64) cc = 64;
            int2 m2 = ev[bB + base + (l < cc ? l : cc - 1)];
            for (int ii = 0; ii < cc; ++ii) {
                int s = __builtin_amdgcn_readlane(m2.x, ii);
                unsigned p = h32[(size_t)s * 64 + l];
                float wq = rl_f(m2.y, ii);
                axB = fmaf(wq, bflo2f(p), axB);
                ayB = fmaf(wq, bfhi2f(p), ayB);
            }
        }

        // epilogue row A
        if (nA < N) {
            float di = __builtin_bit_cast(float, __builtin_amdgcn_readlane(__builtin_bit_cast(int, dv), r));
            float di2 = di * di;
            float ox = fmaf(di2, bflo2f(psA), axA) + bb.x;
            float oy = fmaf(di2, bfhi2f(psA), ayA) + bb.y;
            if (RELU) { ox = fmaxf(ox, 0.f); oy = fmaxf(oy, 0.f); }
            if (OUTF32) reinterpret_cast<float2*>(outp)[(size_t)nA * 64 + l] = make_float2(ox, oy);
            else {
                unsigned po = (unsigned)f2bf(ox) | ((unsigned)f2bf(oy) << 16);
                reinterpret_cast<unsigned*>(outp)[(size_t)nA * 64 + l] = po;
            }
        }
        // epilogue row B
        if (nB < N) {
            float di = __builtin_bit_cast(float, __builtin_amdgcn_readlane(__builtin_bit_cast(int, dv), r + 1));
            float di2 = di * di;
            float ox = fmaf(di2, bflo2f(psB), axB) + bb.x;
            float oy = fmaf(di2, bfhi2f(psB), ayB) + bb.y;
            if (RELU) { ox = fmaxf(ox, 0.f); oy = fmaxf(oy, 0.f); }
            if (OUTF32) reinterpret_cast<float2*>(outp)[(size_t)nB * 64 + l] = make_float2(ox, oy);
            else {
                unsigned po = (unsigned)f2bf(ox) | ((unsigned)f2bf(oy) << 16);
                reinterpret_cast<unsigned*>(outp)[(size_t)nB * 64 + l] = po;
            }
        }
    }
}

extern "C" void kernel_launch(void* const* d_in, const int* in_sizes, int n_in,
                              void* d_out, int out_size, void* d_ws, size_t ws_size,
                              hipStream_t stream) {
    const float* x  = (const float*)d_in[0];
    const int*   ei = (const int*)d_in[1];
    const float* W1 = (const float*)d_in[2];
    const float* b1 = (const float*)d_in[3];
    const float* W2 = (const float*)d_in[4];
    const float* b2 = (const float*)d_in[5];
    // Wq/bq/Wk/bk (6..9) dead: softmax over seq_len=1 is identity.
    const float* Wv = (const float*)d_in[10];
    const float* bv = (const float*)d_in[11];
    const float* Wo = (const float*)d_in[12];
    const float* bo = (const float*)d_in[13];
    int N = in_sizes[0] / DD;
    int E = in_sizes[1] / 2;
    const int* src = ei;
    const int* dst = ei + E;
    float* out = (float*)d_out;

    unsigned* hA  = (unsigned*)d_ws;                  // N*64 u32 (bf16 GEMM out)
    unsigned* h1  = hA + (size_t)N * 64;              // N*64 u32 (bf16 h1)
    float* dinv   = (float*)(h1 + (size_t)N * 64);    // N
    float* Wf     = dinv + N;                         // 128*128 f32
    float* bfo    = Wf + DD * DD;                     // 128
    float* bf2    = bfo + DD;                         // 128
    unsigned short* Wt1  = (unsigned short*)(bf2 + DD);   // 128*128 bf16
    unsigned short* W2ft = Wt1 + DD * DD;                 // 128*128 bf16
    int* cnt    = (int*)(W2ft + DD * DD);             // N
    int* fillc  = cnt + N;                            // N
    int* rowptr = fillc + N;                          // N+1
    int* bsums  = rowptr + N + 1;                     // 512
    int2* ev    = (int2*)(((uintptr_t)(bsums + 512) + 15) & ~(uintptr_t)15);  // E

    int nb = (N + 255) / 256;
    int EB = (E + 255) / 256;

    // D1: zero counters
    k_zero<<<512, 256, 0, stream>>>(cnt, fillc, N);
    // D2: degree histogram + MHA weight fold (independent block ranges)
    k_hist_fuse1<<<EB + 129, 256, 0, stream>>>(dst, cnt, E, N, Wv, Wo, bv, bo, Wf, bfo, EB);
    // D3: block-level scan + weight transposes (needs Wf from D2)
    k_scanblk_wprep<<<nb + 129, 256, 0, stream>>>(cnt, rowptr, bsums, N, nb,
                                                  W2, Wf, b2, bfo, W2ft, bf2, W1, Wt1);
    // D4: scan finalize (inline bsums scan) + dinv
    k_scan_add2<<<nb, 256, 0, stream>>>(rowptr, bsums, cnt, dinv, N, nb);
    // D5: CSR fill
    k_fill<<<EB, 256, 0, stream>>>(src, dst, rowptr, fillc, dinv, ev, E, N);
    // D6: layer-1 GEMM: hA = bf16(x @ W1)   (grid 512, R9-proven)
    k_gemm_mfma<1><<<512, 256, 0, stream>>>(x, Wt1, (unsigned short*)hA, N);
    int gb = ((N + 7) / 8 + 3) / 4;   // 4 waves/block, 8 rows/wave
    // D7: gather layer 1 -> h1 (bf16, relu, +b1)
    k_gather8<0, 1><<<gb, 256, 0, stream>>>(rowptr, ev, hA, dinv, b1, h1, N);
    // D8: layer-2 GEMM (W2·Wv·Wo folded): hA = bf16(h1 @ W2f)
    k_gemm_mfma<0><<<512, 256, 0, stream>>>(h1, W2ft, (unsigned short*)hA, N);
    // D9: gather layer 2 -> out (f32, +bf2)
    k_gather8<1, 0><<<gb, 256, 0, stream>>>(rowptr, ev, hA, dinv, bf2, out, N);
}

// Round 13
// 186.903 us; speedup vs baseline: 1.1476x; 1.0105x over previous
//
#include <hip/hip_runtime.h>
#include <hip/hip_bf16.h>

#define DD 128

typedef __bf16 bf16x8v __attribute__((ext_vector_type(8)));
typedef float  f32x4   __attribute__((ext_vector_type(4)));

__device__ inline unsigned short f2bf(float f) {
    unsigned u = __builtin_bit_cast(unsigned, f);
    unsigned r = (u + 0x7fffu + ((u >> 16) & 1u)) >> 16;
    return (unsigned short)r;
}
__device__ inline float bflo2f(unsigned p) { return __builtin_bit_cast(float, p << 16); }
__device__ inline float bfhi2f(unsigned p) { return __builtin_bit_cast(float, p & 0xffff0000u); }
__device__ inline float rl_f(int v, int i) {
    return __builtin_bit_cast(float, __builtin_amdgcn_readlane(v, i));
}

// ---- zero cnt + fillc ----
__global__ __launch_bounds__(256) void k_zero(int* __restrict__ a, int* __restrict__ b, int N) {
    int i = blockIdx.x * 256 + threadIdx.x;
    int stride = gridDim.x * 256;
    for (; i < N; i += stride) { a[i] = 0; b[i] = 0; }
}

// ---- hist + fuse1 (Wf = Wv@Wo, bfo = bv@Wo + bo) in one dispatch ----
__global__ __launch_bounds__(256) void k_hist_fuse1(const int* __restrict__ dst, int* __restrict__ cnt,
                                                    int E, int N,
                                                    const float* __restrict__ Wv, const float* __restrict__ Wo,
                                                    const float* __restrict__ bv, const float* __restrict__ bo,
                                                    float* __restrict__ Wf, float* __restrict__ bfo, int EB) {
    if ((int)blockIdx.x < EB) {
        int e = blockIdx.x * 256 + threadIdx.x;
        if (e < E) {
            int d = dst[e];
            if ((unsigned)d < (unsigned)N) atomicAdd(&cnt[d], 1);
        }
    } else {
        int gid = (blockIdx.x - EB) * 256 + threadIdx.x;
        if (gid >= (DD + 1) * DD) return;
        int i = gid >> 7, j = gid & (DD - 1);
        if (i < DD) {
            float acc = 0.f;
            for (int k = 0; k < DD; ++k) acc = fmaf(Wv[i * DD + k], Wo[k * DD + j], acc);
            Wf[i * DD + j] = acc;
        } else {
            float acc = bo[j];
            for (int k = 0; k < DD; ++k) acc = fmaf(bv[k], Wo[k * DD + j], acc);
            bfo[j] = acc;
        }
    }
}

// ---- block scan + weight prep (W2f^T bf16, bf2, Wt1) in one dispatch ----
__global__ __launch_bounds__(256) void k_scanblk_wprep(const int* __restrict__ cnt, int* __restrict__ rowptr,
                                                       int* __restrict__ bsums, int N, int nb,
                                                       const float* __restrict__ W2, const float* __restrict__ Wf,
                                                       const float* __restrict__ b2, const float* __restrict__ bfo,
                                                       unsigned short* __restrict__ W2ft, float* __restrict__ bf2,
                                                       const float* __restrict__ W1, unsigned short* __restrict__ Wt1) {
    if ((int)blockIdx.x < nb) {
        __shared__ int sh[256];
        int t = threadIdx.x;
        int gid = blockIdx.x * 256 + t;
        int v = (gid < N) ? cnt[gid] : 0;
        sh[t] = v;
        __syncthreads();
        #pragma unroll
        for (int off = 1; off < 256; off <<= 1) {
            int add = (t >= off) ? sh[t - off] : 0;
            __syncthreads();
            sh[t] += add;
            __syncthreads();
        }
        if (gid < N) rowptr[gid] = sh[t] - v;
        if (t == 255) bsums[blockIdx.x] = sh[255];
    } else {
        int blk = blockIdx.x - nb;
        if (blk < 65) {
            int gid = blk * 256 + threadIdx.x;
            if (gid >= (DD + 1) * DD) return;
            int i = gid >> 7, j = gid & (DD - 1);
            if (i < DD) {
                float acc = 0.f;
                for (int k = 0; k < DD; ++k) acc = fmaf(W2[i * DD + k], Wf[k * DD + j], acc);
                W2ft[j * DD + i] = f2bf(acc);       // transposed bf16
            } else {
                float acc = bfo[j];
                for (int k = 0; k < DD; ++k) acc = fmaf(b2[k], Wf[k * DD + j], acc);
                bf2[j] = acc;
            }
        } else {
            int gid = (blk - 65) * 256 + threadIdx.x;   // 16384
            int k = gid >> 7, n = gid & 127;
            Wt1[n * DD + k] = f2bf(W1[k * DD + n]);
        }
    }
}

// ---- scan finalize with inline bsums scan ----
__global__ __launch_bounds__(256) void k_scan_add2(int* __restrict__ rowptr, const int* __restrict__ bsums,
                                                   const int* __restrict__ cnt, float* __restrict__ dinv,
                                                   int N, int nb) {
    __shared__ int sh[512];
    int t = threadIdx.x;
    sh[t]       = (t < nb)       ? bsums[t]       : 0;
    sh[t + 256] = (t + 256 < nb) ? bsums[t + 256] : 0;
    __syncthreads();
    #pragma unroll
    for (int off = 1; off < 512; off <<= 1) {
        int a = (t >= off)       ? sh[t - off]       : 0;
        int b = (t + 256 >= off) ? sh[t + 256 - off] : 0;
        __syncthreads();
        sh[t] += a;
        sh[t + 256] += b;
        __syncthreads();
    }
    int b = blockIdx.x;
    int pfx = (b == 0) ? 0 : sh[b - 1];
    int gid = b * 256 + t;
    if (gid < N) {
        int c = cnt[gid];
        int v = rowptr[gid] + pfx;
        rowptr[gid] = v;
        if (gid == N - 1) rowptr[N] = v + c;
        dinv[gid] = rsqrtf(1.0f + (float)c);
    }
}

// ---- fill CSR: ev[pos] = (src, bits(norm)) grouped by dst ----
__global__ __launch_bounds__(256) void k_fill(const int* __restrict__ src, const int* __restrict__ dst,
                                              const int* __restrict__ rowptr, int* __restrict__ fillc,
                                              const float* __restrict__ dinv,
                                              int2* __restrict__ ev, int E, int N) {
    int e = blockIdx.x * 256 + threadIdx.x;
    if (e >= E) return;
    int s = src[e], d = dst[e];
    if ((unsigned)s >= (unsigned)N || (unsigned)d >= (unsigned)N) return;
    int pos = rowptr[d] + atomicAdd(&fillc[d], 1);
    float nm = dinv[s] * dinv[d];
    ev[pos] = make_int2(s, __builtin_bit_cast(int, nm));
}

// ---- MFMA GEMM: Cb[M x 128] bf16 = A[M x 128] @ Wt^T ----
// B fragments preloaded in registers; no LDS, no syncthreads. Grid 512 (R9-proven).
// Layouts (m89/m91): a/b frag: idx=l&15, k=(l>>4)*8+j; D: col=l&15, row=(l>>4)*4+reg.
template<int AF32>
__global__ __launch_bounds__(256, 2) void k_gemm_mfma(const void* __restrict__ Av,
                                                      const unsigned short* __restrict__ Wt,
                                                      unsigned short* __restrict__ Cb, int M) {
    int w  = threadIdx.x >> 6;
    int l  = threadIdx.x & 63;
    int lr = l & 15, lg = l >> 4;

    bf16x8v bfr[8][4];
    #pragma unroll
    for (int nt = 0; nt < 8; ++nt)
        #pragma unroll
        for (int kk = 0; kk < 4; ++kk)
            bfr[nt][kk] = *reinterpret_cast<const bf16x8v*>(Wt + (nt * 16 + lr) * DD + kk * 32 + lg * 8);

    int tiles = (M + 63) >> 6;
    for (int t = blockIdx.x; t < tiles; t += gridDim.x) {
        int m0 = t * 64 + w * 16;
        int row = m0 + lr;
        int rowc = row < M ? row : (M - 1);

        bf16x8v af[4];
        if (AF32) {
            const float* Af = (const float*)Av;
            #pragma unroll
            for (int kk = 0; kk < 4; ++kk) {
                const float* p = Af + (size_t)rowc * DD + kk * 32 + lg * 8;
                float4 u0 = *reinterpret_cast<const float4*>(p);
                float4 u1 = *reinterpret_cast<const float4*>(p + 4);
                af[kk][0] = (__bf16)u0.x; af[kk][1] = (__bf16)u0.y;
                af[kk][2] = (__bf16)u0.z; af[kk][3] = (__bf16)u0.w;
                af[kk][4] = (__bf16)u1.x; af[kk][5] = (__bf16)u1.y;
                af[kk][6] = (__bf16)u1.z; af[kk][7] = (__bf16)u1.w;
            }
        } else {
            const unsigned short* Ab = (const unsigned short*)Av;
            #pragma unroll
            for (int kk = 0; kk < 4; ++kk)
                af[kk] = *reinterpret_cast<const bf16x8v*>(Ab + (size_t)rowc * DD + kk * 32 + lg * 8);
        }

        f32x4 acc[8] = {};
        #pragma unroll
        for (int kk = 0; kk < 4; ++kk)
            #pragma unroll
            for (int nt = 0; nt < 8; ++nt)
                acc[nt] = __builtin_amdgcn_mfma_f32_16x16x32_bf16(af[kk], bfr[nt][kk], acc[nt], 0, 0, 0);

        #pragma unroll
        for (int nt = 0; nt < 8; ++nt)
            #pragma unroll
            for (int r = 0; r < 4; ++r) {
                int rr = m0 + lg * 4 + r;
                if (rr < M) Cb[(size_t)rr * DD + nt * 16 + lr] = f2bf(acc[nt][r]);
            }
    }
}

// ---- CSR gather v7: 4 rows/wave, ALL loads issued upfront ----
// Per wave: 4 chunk loads -> 32 row loads + 4 self loads in flight (36 VMEM),
// one drain, then pure FMA. All register arrays compile-time-indexed.
template<int OUTF32, int RELU>
__global__ __launch_bounds__(256) void k_gather4(const int* __restrict__ rowptr, const int2* __restrict__ ev,
                                                 const unsigned* __restrict__ h32, const float* __restrict__ dinv,
                                                 const float* __restrict__ bias, void* __restrict__ outp, int N) {
    int l = threadIdx.x & 63;
    int g = blockIdx.x * 4 + (threadIdx.x >> 6);   // 4-row group id
    int m0 = g * 4;
    if (m0 >= N) return;
    float2 bb = reinterpret_cast<const float2*>(bias)[l];

    // preload 5 row ptrs (lanes 0..4) and 4 dinv (lanes 0..3)
    int rpidx = m0 + l; if (rpidx > N) rpidx = N;
    int rp = (l < 5) ? rowptr[rpidx] : 0;
    int dvidx = m0 + l; if (dvidx >= N) dvidx = N - 1;
    float dv = (l < 4) ? dinv[dvidx] : 0.f;

    int bs[5];
    #pragma unroll
    for (int i = 0; i < 5; ++i) bs[i] = __builtin_amdgcn_readlane(rp, i);

    // 4 independent edge-chunk loads
    int deg[4], c[4];
    int2 me[4];
    #pragma unroll
    for (int r = 0; r < 4; ++r) {
        deg[r] = bs[r + 1] - bs[r];
        int cc = deg[r] > 64 ? 64 : deg[r];
        c[r] = cc;
        me[r] = (cc > 0) ? ev[bs[r] + (l < cc ? l : cc - 1)] : make_int2(0, 0);
    }

    // upfront: 32 row loads + 4 self loads, no consumption yet
    unsigned p[4][8]; float w[4][8];
    #pragma unroll
    for (int r = 0; r < 4; ++r) {
        int f = c[r] < 8 ? c[r] : 8;
        #pragma unroll
        for (int q = 0; q < 8; ++q) {
            int i = (q < f) ? q : (f > 0 ? f - 1 : 0);
            int s = __builtin_amdgcn_readlane(me[r].x, i);
            p[r][q] = h32[(size_t)s * 64 + l];
            w[r][q] = (q < f) ? rl_f(me[r].y, i) : 0.f;
        }
    }
    unsigned ps[4];
    #pragma unroll
    for (int r = 0; r < 4; ++r) {
        int n = m0 + r; int nc = n < N ? n : N - 1;
        ps[r] = h32[(size_t)nc * 64 + l];
    }

    float ax[4] = {0.f, 0.f, 0.f, 0.f}, ay[4] = {0.f, 0.f, 0.f, 0.f};
    #pragma unroll
    for (int r = 0; r < 4; ++r)
        #pragma unroll
        for (int q = 0; q < 8; ++q) {
            ax[r] = fmaf(w[r][q], bflo2f(p[r][q]), ax[r]);
            ay[r] = fmaf(w[r][q], bfhi2f(p[r][q]), ay[r]);
        }

    // deg in (8,64]: continue within prefetched chunks; deg > 64: serial tail (rare)
    #pragma unroll
    for (int r = 0; r < 4; ++r) {
        for (int i = 8; i < c[r]; i += 8) {
            #pragma unroll
            for (int q = 0; q < 8; ++q) {
                int ii = (i + q < c[r]) ? i + q : c[r] - 1;
                int s = __builtin_amdgcn_readlane(me[r].x, ii);
                unsigned pp = h32[(size_t)s * 64 + l];
                float wq = (i + q < c[r]) ? rl_f(me[r].y, ii) : 0.f;
                ax[r] = fmaf(wq, bflo2f(pp), ax[r]);
                ay[r] = fmaf(wq, bfhi2f(pp), ay[r]);
            }
        }
        for (int base = 64; base < deg[r]; base += 64) {
            int cc = deg[r] - base; if (cc > 64) cc = 64;
            int2 m2 = ev[bs[r] + base + (l < cc ? l : cc - 1)];
            for (int ii = 0; ii < cc; ++ii) {
                int s = __builtin_amdgcn_readlane(m2.x, ii);
                unsigned pp = h32[(size_t)s * 64 + l];
                float wq = rl_f(m2.y, ii);
                ax[r] = fmaf(wq, bflo2f(pp), ax[r]);
                ay[r] = fmaf(wq, bfhi2f(pp), ay[r]);
            }
        }
    }

    // epilogue
    #pragma unroll
    for (int r = 0; r < 4; ++r) {
        int n = m0 + r;
        if (n < N) {
            float di = __builtin_bit_cast(float, __builtin_amdgcn_readlane(__builtin_bit_cast(int, dv), r));
            float di2 = di * di;
            float ox = fmaf(di2, bflo2f(ps[r]), ax[r]) + bb.x;
            float oy = fmaf(di2, bfhi2f(ps[r]), ay[r]) + bb.y;
            if (RELU) { ox = fmaxf(ox, 0.f); oy = fmaxf(oy, 0.f); }
            if (OUTF32) {
                reinterpret_cast<float2*>(outp)[(size_t)n * 64 + l] = make_float2(ox, oy);
            } else {
                unsigned po = (unsigned)f2bf(ox) | ((unsigned)f2bf(oy) << 16);
                reinterpret_cast<unsigned*>(outp)[(size_t)n * 64 + l] = po;
            }
        }
    }
}

extern "C" void kernel_launch(void* const* d_in, const int* in_sizes, int n_in,
                              void* d_out, int out_size, void* d_ws, size_t ws_size,
                              hipStream_t stream) {
    const float* x  = (const float*)d_in[0];
    const int*   ei = (const int*)d_in[1];
    const float* W1 = (const float*)d_in[2];
    const float* b1 = (const float*)d_in[3];
    const float* W2 = (const float*)d_in[4];
    const float* b2 = (const float*)d_in[5];
    // Wq/bq/Wk/bk (6..9) dead: softmax over seq_len=1 is identity.
    const float* Wv = (const float*)d_in[10];
    const float* bv = (const float*)d_in[11];
    const float* Wo = (const float*)d_in[12];
    const float* bo = (const float*)d_in[13];
    int N = in_sizes[0] / DD;
    int E = in_sizes[1] / 2;
    const int* src = ei;
    const int* dst = ei + E;
    float* out = (float*)d_out;

    unsigned* hA  = (unsigned*)d_ws;                  // N*64 u32 (bf16 GEMM out)
    unsigned* h1  = hA + (size_t)N * 64;              // N*64 u32 (bf16 h1)
    float* dinv   = (float*)(h1 + (size_t)N * 64);    // N
    float* Wf     = dinv + N;                         // 128*128 f32
    float* bfo    = Wf + DD * DD;                     // 128
    float* bf2    = bfo + DD;                         // 128
    unsigned short* Wt1  = (unsigned short*)(bf2 + DD);   // 128*128 bf16
    unsigned short* W2ft = Wt1 + DD * DD;                 // 128*128 bf16
    int* cnt    = (int*)(W2ft + DD * DD);             // N
    int* fillc  = cnt + N;                            // N
    int* rowptr = fillc + N;                          // N+1
    int* bsums  = rowptr + N + 1;                     // 512
    int2* ev    = (int2*)(((uintptr_t)(bsums + 512) + 15) & ~(uintptr_t)15);  // E

    int nb = (N + 255) / 256;
    int EB = (E + 255) / 256;

    // D1: zero counters
    k_zero<<<512, 256, 0, stream>>>(cnt, fillc, N);
    // D2: degree histogram + MHA weight fold (independent block ranges)
    k_hist_fuse1<<<EB + 129, 256, 0, stream>>>(dst, cnt, E, N, Wv, Wo, bv, bo, Wf, bfo, EB);
    // D3: block-level scan + weight transposes (needs Wf from D2)
    k_scanblk_wprep<<<nb + 129, 256, 0, stream>>>(cnt, rowptr, bsums, N, nb,
                                                  W2, Wf, b2, bfo, W2ft, bf2, W1, Wt1);
    // D4: scan finalize (inline bsums scan) + dinv
    k_scan_add2<<<nb, 256, 0, stream>>>(rowptr, bsums, cnt, dinv, N, nb);
    // D5: CSR fill
    k_fill<<<EB, 256, 0, stream>>>(src, dst, rowptr, fillc, dinv, ev, E, N);
    // D6: layer-1 GEMM: hA = bf16(x @ W1)
    k_gemm_mfma<1><<<512, 256, 0, stream>>>(x, Wt1, (unsigned short*)hA, N);
    int gb = (N + 15) / 16;   // 4 waves/block, 4 rows/wave
    // D7: gather layer 1 -> h1 (bf16, relu, +b1)
    k_gather4<0, 1><<<gb, 256, 0, stream>>>(rowptr, ev, hA, dinv, b1, h1, N);
    // D8: layer-2 GEMM (W2·Wv·Wo folded): hA = bf16(h1 @ W2f)
    k_gemm_mfma<0><<<512, 256, 0, stream>>>(h1, W2ft, (unsigned short*)hA, N);
    // D9: gather layer 2 -> out (f32, +bf2)
    k_gather4<1, 0><<<gb, 256, 0, stream>>>(rowptr, ev, hA, dinv, bf2, out, N);
}

// Round 15
// 164.923 us; speedup vs baseline: 1.3006x; 1.1333x over previous
//
#include <hip/hip_runtime.h>
#include <hip/hip_bf16.h>

#define DD 128
#define CAP 32
#define OVF_MAX 8192

typedef __bf16 bf16x8v __attribute__((ext_vector_type(8)));
typedef float  f32x4   __attribute__((ext_vector_type(4)));

__device__ inline unsigned short f2bf(float f) {
    unsigned u = __builtin_bit_cast(unsigned, f);
    unsigned r = (u + 0x7fffu + ((u >> 16) & 1u)) >> 16;
    return (unsigned short)r;
}
__device__ inline float bflo2f(unsigned p) { return __builtin_bit_cast(float, p << 16); }
__device__ inline float bfhi2f(unsigned p) { return __builtin_bit_cast(float, p & 0xffff0000u); }
__device__ inline float rl_f(int v, int i) {
    return __builtin_bit_cast(float, __builtin_amdgcn_readlane(v, i));
}

// ---- zero fillc[N] + ovfcnt ----
__global__ __launch_bounds__(256) void k_zero(int* __restrict__ a, int N) {
    int i = blockIdx.x * 256 + threadIdx.x;
    int stride = gridDim.x * 256;
    for (; i <= N; i += stride) a[i] = 0;   // N fillc + 1 ovfcnt (a[N])
}

// ---- padded fill (no scan, no hist!) + fuse1 (Wf = Wv@Wo, bfo = bv@Wo+bo) ----
__global__ __launch_bounds__(256) void k_fill_fuse1(const int* __restrict__ src, const int* __restrict__ dst,
                                                    int* __restrict__ fillc, int* __restrict__ srcp,
                                                    int* __restrict__ ovfcnt, int2* __restrict__ ovf,
                                                    int E, int N, int EB,
                                                    const float* __restrict__ Wv, const float* __restrict__ Wo,
                                                    const float* __restrict__ bv, const float* __restrict__ bo,
                                                    float* __restrict__ Wf, float* __restrict__ bfo) {
    if ((int)blockIdx.x < EB) {
        int e = blockIdx.x * 256 + threadIdx.x;
        if (e >= E) return;
        int s = src[e], d = dst[e];
        if ((unsigned)s >= (unsigned)N || (unsigned)d >= (unsigned)N) return;
        int pos = atomicAdd(&fillc[d], 1);
        if (pos < CAP) srcp[(size_t)d * CAP + pos] = s;
        else {
            int op = atomicAdd(ovfcnt, 1);
            if (op < OVF_MAX) ovf[op] = make_int2(s, d);
        }
    } else {
        int gid = (blockIdx.x - EB) * 256 + threadIdx.x;
        if (gid >= (DD + 1) * DD) return;
        int i = gid >> 7, j = gid & (DD - 1);
        if (i < DD) {
            float acc = 0.f;
            for (int k = 0; k < DD; ++k) acc = fmaf(Wv[i * DD + k], Wo[k * DD + j], acc);
            Wf[i * DD + j] = acc;
        } else {
            float acc = bo[j];
            for (int k = 0; k < DD; ++k) acc = fmaf(bv[k], Wo[k * DD + j], acc);
            bfo[j] = acc;
        }
    }
}

// ---- dinv from fillc + weight prep (W2f^T bf16, bf2, Wt1) ----
__global__ __launch_bounds__(256) void k_dinv_wprep(const int* __restrict__ fillc, float* __restrict__ dinv,
                                                    int N, int nb,
                                                    const float* __restrict__ W2, const float* __restrict__ Wf,
                                                    const float* __restrict__ b2, const float* __restrict__ bfo,
                                                    unsigned short* __restrict__ W2ft, float* __restrict__ bf2,
                                                    const float* __restrict__ W1, unsigned short* __restrict__ Wt1) {
    if ((int)blockIdx.x < nb) {
        int n = blockIdx.x * 256 + threadIdx.x;
        if (n < N) dinv[n] = rsqrtf(1.0f + (float)fillc[n]);
    } else {
        int blk = blockIdx.x - nb;
        if (blk < 65) {
            int gid = blk * 256 + threadIdx.x;
            if (gid >= (DD + 1) * DD) return;
            int i = gid >> 7, j = gid & (DD - 1);
            if (i < DD) {
                float acc = 0.f;
                for (int k = 0; k < DD; ++k) acc = fmaf(W2[i * DD + k], Wf[k * DD + j], acc);
                W2ft[j * DD + i] = f2bf(acc);       // transposed bf16
            } else {
                float acc = bfo[j];
                for (int k = 0; k < DD; ++k) acc = fmaf(b2[k], Wf[k * DD + j], acc);
                bf2[j] = acc;
            }
        } else {
            int gid = (blk - 65) * 256 + threadIdx.x;   // 16384
            int k = gid >> 7, n = gid & 127;
            Wt1[n * DD + k] = f2bf(W1[k * DD + n]);
        }
    }
}

// ---- MFMA GEMM: Cb[M x 128] bf16 = A[M x 128] @ Wt^T ----
// B fragments preloaded in registers; no LDS, no syncthreads. Grid 512 (R9-proven).
// Layouts (m89/m91): a/b frag: idx=l&15, k=(l>>4)*8+j; D: col=l&15, row=(l>>4)*4+reg.
template<int AF32>
__global__ __launch_bounds__(256, 2) void k_gemm_mfma(const void* __restrict__ Av,
                                                      const unsigned short* __restrict__ Wt,
                                                      unsigned short* __restrict__ Cb, int M) {
    int w  = threadIdx.x >> 6;
    int l  = threadIdx.x & 63;
    int lr = l & 15, lg = l >> 4;

    bf16x8v bfr[8][4];
    #pragma unroll
    for (int nt = 0; nt < 8; ++nt)
        #pragma unroll
        for (int kk = 0; kk < 4; ++kk)
            bfr[nt][kk] = *reinterpret_cast<const bf16x8v*>(Wt + (nt * 16 + lr) * DD + kk * 32 + lg * 8);

    int tiles = (M + 63) >> 6;
    for (int t = blockIdx.x; t < tiles; t += gridDim.x) {
        int m0 = t * 64 + w * 16;
        int row = m0 + lr;
        int rowc = row < M ? row : (M - 1);

        bf16x8v af[4];
        if (AF32) {
            const float* Af = (const float*)Av;
            #pragma unroll
            for (int kk = 0; kk < 4; ++kk) {
                const float* p = Af + (size_t)rowc * DD + kk * 32 + lg * 8;
                float4 u0 = *reinterpret_cast<const float4*>(p);
                float4 u1 = *reinterpret_cast<const float4*>(p + 4);
                af[kk][0] = (__bf16)u0.x; af[kk][1] = (__bf16)u0.y;
                af[kk][2] = (__bf16)u0.z; af[kk][3] = (__bf16)u0.w;
                af[kk][4] = (__bf16)u1.x; af[kk][5] = (__bf16)u1.y;
                af[kk][6] = (__bf16)u1.z; af[kk][7] = (__bf16)u1.w;
            }
        } else {
            const unsigned short* Ab = (const unsigned short*)Av;
            #pragma unroll
            for (int kk = 0; kk < 4; ++kk)
                af[kk] = *reinterpret_cast<const bf16x8v*>(Ab + (size_t)rowc * DD + kk * 32 + lg * 8);
        }

        f32x4 acc[8] = {};
        #pragma unroll
        for (int kk = 0; kk < 4; ++kk)
            #pragma unroll
            for (int nt = 0; nt < 8; ++nt)
                acc[nt] = __builtin_amdgcn_mfma_f32_16x16x32_bf16(af[kk], bfr[nt][kk], acc[nt], 0, 0, 0);

        #pragma unroll
        for (int nt = 0; nt < 8; ++nt)
            #pragma unroll
            for (int r = 0; r < 4; ++r) {
                int rr = m0 + lg * 4 + r;
                if (rr < M) Cb[(size_t)rr * DD + nt * 16 + lr] = f2bf(acc[nt][r]);
            }
    }
}

// ---- padded-CSR gather: 4 rows/wave, all loads upfront, dinv[d] factored out ----
// acc = sum_e dinv[src]*h[src]; out = dinv[d]*acc + dinv[d]^2*h[d] + bias
template<int OUTF32, int RELU>
__global__ __launch_bounds__(256) void k_gather_pad(const int* __restrict__ fillc, const int* __restrict__ srcp,
                                                    const float* __restrict__ dinv, const unsigned* __restrict__ h32,
                                                    const float* __restrict__ bias, void* __restrict__ outp,
                                                    int N, const int* __restrict__ ovfcnt, const int2* __restrict__ ovf) {
    int l = threadIdx.x & 63;
    int g = blockIdx.x * 4 + (threadIdx.x >> 6);   // 4-row group id
    int m0 = g * 4;
    if (m0 >= N) return;
    float2 bb = reinterpret_cast<const float2*>(bias)[l];

    // degrees for the 4 rows (lanes 0..3)
    int fcidx = m0 + l; if (fcidx >= N) fcidx = N - 1;
    int fc = (l < 4) ? fillc[fcidx] : 0;

    int deg[4], c[4], sv[4], wvb[4];
    #pragma unroll
    for (int r = 0; r < 4; ++r) {
        deg[r] = __builtin_amdgcn_readlane(fc, r);
        int cc = deg[r] > CAP ? CAP : deg[r];
        c[r] = cc;
        int row = (m0 + r < N) ? (m0 + r) : (N - 1);
        sv[r] = (cc > 0) ? srcp[(size_t)row * CAP + (l < cc ? l : cc - 1)] : 0;
    }
    #pragma unroll
    for (int r = 0; r < 4; ++r)
        wvb[r] = __builtin_bit_cast(int, dinv[sv[r]]);   // per-lane gather of dinv[src]

    // upfront: 32 row loads + 4 self loads in flight before any consumption
    unsigned p[4][8]; float w[4][8];
    #pragma unroll
    for (int r = 0; r < 4; ++r) {
        int f = c[r] < 8 ? c[r] : 8;
        #pragma unroll
        for (int q = 0; q < 8; ++q) {
            int i = (q < f) ? q : (f > 0 ? f - 1 : 0);
            int s = __builtin_amdgcn_readlane(sv[r], i);
            p[r][q] = h32[(size_t)s * 64 + l];
            w[r][q] = (q < f) ? rl_f(wvb[r], i) : 0.f;
        }
    }
    unsigned ps[4];
    #pragma unroll
    for (int r = 0; r < 4; ++r) {
        int n = m0 + r; int nc = n < N ? n : N - 1;
        ps[r] = h32[(size_t)nc * 64 + l];
    }

    float ax[4] = {0.f, 0.f, 0.f, 0.f}, ay[4] = {0.f, 0.f, 0.f, 0.f};
    #pragma unroll
    for (int r = 0; r < 4; ++r)
        #pragma unroll
        for (int q = 0; q < 8; ++q) {
            ax[r] = fmaf(w[r][q], bflo2f(p[r][q]), ax[r]);
            ay[r] = fmaf(w[r][q], bfhi2f(p[r][q]), ay[r]);
        }

    // deg in (8,32]: remaining batches within the (fully loaded) chunk registers
    #pragma unroll
    for (int r = 0; r < 4; ++r) {
        for (int i = 8; i < c[r]; i += 8) {
            #pragma unroll
            for (int q = 0; q < 8; ++q) {
                int ii = (i + q < c[r]) ? i + q : c[r] - 1;
                int s = __builtin_amdgcn_readlane(sv[r], ii);
                unsigned pp = h32[(size_t)s * 64 + l];
                float wq = (i + q < c[r]) ? rl_f(wvb[r], ii) : 0.f;
                ax[r] = fmaf(wq, bflo2f(pp), ax[r]);
                ay[r] = fmaf(wq, bfhi2f(pp), ay[r]);
            }
        }
    }

    // overflow (deg > CAP): exact fallback, executes zero iterations in practice
    int anyovf = 0;
    #pragma unroll
    for (int r = 0; r < 4; ++r) anyovf |= (deg[r] > CAP) ? 1 : 0;
    if (anyovf) {
        int oc = *ovfcnt; if (oc > OVF_MAX) oc = OVF_MAX;
        for (int i = 0; i < oc; ++i) {
            int2 e = ovf[i];
            #pragma unroll
            for (int r = 0; r < 4; ++r) {
                if (deg[r] > CAP && e.y == m0 + r) {
                    float wq = dinv[e.x];
                    unsigned pp = h32[(size_t)e.x * 64 + l];
                    ax[r] = fmaf(wq, bflo2f(pp), ax[r]);
                    ay[r] = fmaf(wq, bfhi2f(pp), ay[r]);
                }
            }
        }
    }

    // epilogue: out = di*acc + di^2*self + bias
    #pragma unroll
    for (int r = 0; r < 4; ++r) {
        int n = m0 + r;
        if (n < N) {
            float di = rsqrtf(1.0f + (float)deg[r]);
            float di2 = di * di;
            float ox = fmaf(di2, bflo2f(ps[r]), di * ax[r]) + bb.x;
            float oy = fmaf(di2, bfhi2f(ps[r]), di * ay[r]) + bb.y;
            if (RELU) { ox = fmaxf(ox, 0.f); oy = fmaxf(oy, 0.f); }
            if (OUTF32) {
                reinterpret_cast<float2*>(outp)[(size_t)n * 64 + l] = make_float2(ox, oy);
            } else {
                unsigned po = (unsigned)f2bf(ox) | ((unsigned)f2bf(oy) << 16);
                reinterpret_cast<unsigned*>(outp)[(size_t)n * 64 + l] = po;
            }
        }
    }
}

extern "C" void kernel_launch(void* const* d_in, const int* in_sizes, int n_in,
                              void* d_out, int out_size, void* d_ws, size_t ws_size,
                              hipStream_t stream) {
    const float* x  = (const float*)d_in[0];
    const int*   ei = (const int*)d_in[1];
    const float* W1 = (const float*)d_in[2];
    const float* b1 = (const float*)d_in[3];
    const float* W2 = (const float*)d_in[4];
    const float* b2 = (const float*)d_in[5];
    // Wq/bq/Wk/bk (6..9) dead: softmax over seq_len=1 is identity.
    const float* Wv = (const float*)d_in[10];
    const float* bv = (const float*)d_in[11];
    const float* Wo = (const float*)d_in[12];
    const float* bo = (const float*)d_in[13];
    int N = in_sizes[0] / DD;
    int E = in_sizes[1] / 2;
    const int* src = ei;
    const int* dst = ei + E;
    float* out = (float*)d_out;

    unsigned* hA  = (unsigned*)d_ws;                  // N*64 u32 (bf16 GEMM out)
    unsigned* h1  = hA + (size_t)N * 64;              // N*64 u32 (bf16 h1)
    float* dinv   = (float*)(h1 + (size_t)N * 64);    // N
    float* Wf     = dinv + N;                         // 128*128 f32
    float* bfo    = Wf + DD * DD;                     // 128
    float* bf2    = bfo + DD;                         // 128
    unsigned short* Wt1  = (unsigned short*)(bf2 + DD);   // 128*128 bf16
    unsigned short* W2ft = Wt1 + DD * DD;                 // 128*128 bf16
    int* fillc  = (int*)(W2ft + DD * DD);             // N (+1 for ovfcnt)
    int* ovfcnt = fillc + N;                          // 1
    int2* ovf   = (int2*)(((uintptr_t)(ovfcnt + 1) + 15) & ~(uintptr_t)15);   // OVF_MAX
    int* srcp   = (int*)(ovf + OVF_MAX);              // N*CAP

    int nb = (N + 255) / 256;
    int EB = (E + 255) / 256;

    // D1: zero fillc + ovfcnt
    k_zero<<<512, 256, 0, stream>>>(fillc, N);
    // D2: padded CSR fill (no hist, no scan!) + MHA weight fold
    k_fill_fuse1<<<EB + 129, 256, 0, stream>>>(src, dst, fillc, srcp, ovfcnt, ovf, E, N, EB,
                                               Wv, Wo, bv, bo, Wf, bfo);
    // D3: dinv + weight transposes (needs fillc, Wf from D2)
    k_dinv_wprep<<<nb + 129, 256, 0, stream>>>(fillc, dinv, N, nb,
                                               W2, Wf, b2, bfo, W2ft, bf2, W1, Wt1);
    // D4: layer-1 GEMM: hA = bf16(x @ W1)
    k_gemm_mfma<1><<<512, 256, 0, stream>>>(x, Wt1, (unsigned short*)hA, N);
    int nwaves = (N + 3) / 4;
    int gb = (nwaves + 3) / 4;   // 4 waves/block, 4 rows/wave
    // D5: gather layer 1 -> h1 (bf16, relu, +b1)
    k_gather_pad<0, 1><<<gb, 256, 0, stream>>>(fillc, srcp, dinv, hA, b1, h1, N, ovfcnt, ovf);
    // D6: layer-2 GEMM (W2·Wv·Wo folded): hA = bf16(h1 @ W2f)
    k_gemm_mfma<0><<<512, 256, 0, stream>>>(h1, W2ft, (unsigned short*)hA, N);
    // D7: gather layer 2 -> out (f32, +bf2)
    k_gather_pad<1, 0><<<gb, 256, 0, stream>>>(fillc, srcp, dinv, hA, bf2, out, N, ovfcnt, ovf);
}